// Round 1
// baseline (371.736 us; speedup 1.0000x reference)
//
#include <hip/hip_runtime.h>

// Segmented mean: x[N][64] fp32, segment_ids[N] int (sorted, contiguous),
// lengths[B] int. out[B][64] = segment_sum(x) / lengths.
//
// Memory-bound: 256 MB read -> ~41 us floor at 6.3 TB/s.
// Exploits contiguity of segments: a 512-row block spans <=2 segments
// (min segment length ~8100 rows), so per-block LDS accumulation + one
// global atomicAdd per (block, touched segment, col) keeps atomics ~135K
// total across 4096 addresses.

#define D 64
#define ROWS_PER_BLOCK 512
#define NSLOT 4   // generous: data guarantees <=2 segments per 512-row block

__global__ __launch_bounds__(256) void seg_sum_kernel(
    const float* __restrict__ x,
    const int*   __restrict__ seg,
    float*       __restrict__ acc,   // [B][D] fp32, pre-zeroed
    int n_rows)
{
    __shared__ float lacc[NSLOT][D];
    __shared__ int   lused[NSLOT];
    __shared__ int   lseg0;

    const int tid = threadIdx.x;
    const int r0  = blockIdx.x * ROWS_PER_BLOCK;
    if (r0 >= n_rows) return;  // uniform across block
    int r1 = r0 + ROWS_PER_BLOCK;
    if (r1 > n_rows) r1 = n_rows;

    // init LDS
    for (int i = tid; i < NSLOT * D; i += 256) ((float*)lacc)[i] = 0.0f;
    if (tid < NSLOT) lused[tid] = 0;
    if (tid == 0) lseg0 = seg[r0];
    __syncthreads();
    const int seg0 = lseg0;

    // thread layout: 16 col-groups (float4) x 16 row-lanes
    const int col     = (tid & 15) * 4;   // starting column of this thread's float4
    const int rowlane = tid >> 4;         // 0..15

    float4 a = make_float4(0.f, 0.f, 0.f, 0.f);
    int cur = seg0;

    for (int r = r0 + rowlane; r < r1; r += 16) {
        const int s = seg[r];  // 16 lanes share each value -> coalesces to 16B/wave
        const float4 v = *(const float4*)(x + (size_t)r * D + col);
        if (s == cur) {
            a.x += v.x; a.y += v.y; a.z += v.z; a.w += v.w;
        } else {
            // flush accumulator for segment `cur`
            const int slot = cur - seg0;
            if (slot >= 0 && slot < NSLOT) {
                atomicAdd(&lacc[slot][col + 0], a.x);
                atomicAdd(&lacc[slot][col + 1], a.y);
                atomicAdd(&lacc[slot][col + 2], a.z);
                atomicAdd(&lacc[slot][col + 3], a.w);
                lused[slot] = 1;
            } else {  // safety fallback (shouldn't trigger on this data)
                atomicAdd(&acc[(size_t)cur * D + col + 0], a.x);
                atomicAdd(&acc[(size_t)cur * D + col + 1], a.y);
                atomicAdd(&acc[(size_t)cur * D + col + 2], a.z);
                atomicAdd(&acc[(size_t)cur * D + col + 3], a.w);
            }
            a = v;
            cur = s;
        }
    }
    // final flush
    {
        const int slot = cur - seg0;
        if (slot >= 0 && slot < NSLOT) {
            atomicAdd(&lacc[slot][col + 0], a.x);
            atomicAdd(&lacc[slot][col + 1], a.y);
            atomicAdd(&lacc[slot][col + 2], a.z);
            atomicAdd(&lacc[slot][col + 3], a.w);
            lused[slot] = 1;
        } else {
            atomicAdd(&acc[(size_t)cur * D + col + 0], a.x);
            atomicAdd(&acc[(size_t)cur * D + col + 1], a.y);
            atomicAdd(&acc[(size_t)cur * D + col + 2], a.z);
            atomicAdd(&acc[(size_t)cur * D + col + 3], a.w);
        }
    }
    __syncthreads();

    // one global atomic per touched (segment, col): 256 threads cover 4x64
    for (int i = tid; i < NSLOT * D; i += 256) {
        const int slot = i >> 6;
        const int c    = i & (D - 1);
        if (lused[slot]) {
            atomicAdd(&acc[(size_t)(seg0 + slot) * D + c], lacc[slot][c]);
        }
    }
}

__global__ __launch_bounds__(256) void seg_div_kernel(
    const float* __restrict__ acc,
    const int*   __restrict__ len,
    float*       __restrict__ out,
    int total)
{
    const int i = blockIdx.x * blockDim.x + threadIdx.x;
    if (i < total) {
        out[i] = acc[i] / (float)len[i >> 6];  // i>>6 == segment index (D=64)
    }
}

extern "C" void kernel_launch(void* const* d_in, const int* in_sizes, int n_in,
                              void* d_out, int out_size, void* d_ws, size_t ws_size,
                              hipStream_t stream) {
    const float* x   = (const float*)d_in[0];
    const int*   seg = (const int*)d_in[1];
    const int*   len = (const int*)d_in[2];
    float*       out = (float*)d_out;
    float*       acc = (float*)d_ws;   // [B][D] fp32 accumulator

    const int n_rows = in_sizes[1];            // N = 1048576
    const int B      = in_sizes[2];            // 64
    const int total  = B * D;                  // 4096 == out_size

    // zero the accumulator (ws is poisoned 0xAA before every call)
    hipMemsetAsync(acc, 0, (size_t)total * sizeof(float), stream);

    const int grid1 = (n_rows + ROWS_PER_BLOCK - 1) / ROWS_PER_BLOCK;  // 2048
    seg_sum_kernel<<<grid1, 256, 0, stream>>>(x, seg, acc, n_rows);

    const int grid2 = (total + 255) / 256;
    seg_div_kernel<<<grid2, 256, 0, stream>>>(acc, len, out, total);
}